// Round 13
// baseline (211.689 us; speedup 1.0000x reference)
//
#include <hip/hip_runtime.h>
#include <hip/hip_bf16.h>

// GQA prefill: x@[Wq|Wk|Wv] (rope fused) -> causal GQA flash attention -> @Wo
// B=2 S=2048 D=2048 H=32 Hkv=8 hd=64 G=4. All GEMMs bf16-MFMA, fp32 accum.
// R13: split-KV attention. Empirical law R8-R12: k_attn = longest-chain
// tiles x ~2.4us. Split st>=8 supertiles into 2 half-KV blocks (chain 32->16,
// all 1536 jobs 9-16 tiles, LPT order); halves write normalized bf16
// partials + (m,l); k_comb (512 blocks) merges. Inner loop byte-identical.

#define S_LEN 2048
#define DIM   2048
#define NH    32
#define NKV   8
#define HD    64
#define BS    4096      // B*S rows
#define NQKV  3072      // 2048 q + 512 k + 512 v
#define LL(x) ((long long)(x))

typedef __bf16 bf16x8 __attribute__((ext_vector_type(8)));
typedef float  f32x4  __attribute__((ext_vector_type(4)));
typedef float  f32x16 __attribute__((ext_vector_type(16)));
typedef unsigned u32x4 __attribute__((ext_vector_type(4)));

__device__ __forceinline__ unsigned short bfb(float f) {
  __hip_bfloat16 h = __float2bfloat16(f);
  return *reinterpret_cast<unsigned short*>(&h);
}

__device__ __forceinline__ float bf2f(unsigned short u) {
  return __uint_as_float((unsigned)u << 16);
}

__device__ __forceinline__ unsigned cvtpk(float lo, float hi) {
  unsigned u;
  asm("v_cvt_pk_bf16_f32 %0, %1, %2" : "=v"(u) : "v"(lo), "v"(hi));
  return u;
}

__device__ __forceinline__ void gload16(const void* g, void* l) {
  __builtin_amdgcn_global_load_lds(
      (const __attribute__((address_space(1))) void*)g,
      (__attribute__((address_space(3))) void*)l, 16, 0, 0);
}

// ---- fused preprocessing: rope table + x cast + 4 weight transposes ----
__device__ __forceinline__ void tcast_body(
    const float* __restrict__ in, unsigned short* __restrict__ out,
    int K, int N, int bx, int by, int tid, float* tile /*[32][33]*/) {
  int n0 = bx * 32, k0 = by * 32;
  int tx = tid & 31, ty = tid >> 5;  // 32x8
#pragma unroll
  for (int r = 0; r < 32; r += 8)
    tile[(ty + r) * 33 + tx] = in[LL(k0 + ty + r) * N + n0 + tx];
  __syncthreads();
#pragma unroll
  for (int r = 0; r < 32; r += 8)
    out[LL(n0 + ty + r) * K + k0 + tx] = bfb(tile[tx * 33 + ty + r]);
}

__global__ __launch_bounds__(256) void k_prep(
    const float* __restrict__ x,  const float* __restrict__ Wq,
    const float* __restrict__ Wk, const float* __restrict__ Wv,
    const float* __restrict__ Wo, float* __restrict__ tab,
    unsigned short* __restrict__ xb, unsigned short* __restrict__ wqkvt,
    unsigned short* __restrict__ wot) {
  __shared__ float tile[32 * 33];
  int blk = blockIdx.x, tid = threadIdx.x;
  if (blk < 256) {
    int i = blk * 256 + tid;             // 65536 exact
    int s = i >> 5, f = i & 31;
    double inv = pow(500000.0, -2.0 * (double)f / 64.0);
    double fr = (double)s * inv;
    tab[2 * i]     = (float)cos(fr);
    tab[2 * i + 1] = (float)sin(fr);
  } else if (blk < 8448) {
    int i = (blk - 256) * 256 + tid;
    float4 v = ((const float4*)x)[i];
    ushort4 o;
    o.x = bfb(v.x); o.y = bfb(v.y); o.z = bfb(v.z); o.w = bfb(v.w);
    ((ushort4*)xb)[i] = o;
  } else if (blk < 12544) {
    int t2 = blk - 8448;                 // Wq: grid (64,64)
    tcast_body(Wq, wqkvt, DIM, DIM, t2 & 63, t2 >> 6, tid, tile);
  } else if (blk < 13568) {
    int t3 = blk - 12544;                // Wk: grid (16,64)
    tcast_body(Wk, wqkvt + LL(2048) * DIM, DIM, 512, t3 & 15, t3 >> 4, tid, tile);
  } else if (blk < 14592) {
    int t4 = blk - 13568;                // Wv: grid (16,64)
    tcast_body(Wv, wqkvt + LL(2560) * DIM, DIM, 512, t4 & 15, t4 >> 4, tid, tile);
  } else {
    int t5 = blk - 14592;                // Wo: grid (64,64)
    tcast_body(Wo, wot, DIM, DIM, t5 & 63, t5 >> 6, tid, tile);
  }
}

// ---- bf16 MFMA GEMM: C[M][N] = A[M][K] * Bt[N][K]^T  (m97 structure + T1 swizzle) ----
template <int MODE>
__global__ __launch_bounds__(256, 2) void k_gemm(
    const unsigned short* __restrict__ A, const unsigned short* __restrict__ Bt,
    void* __restrict__ Cout, int M, int N, int K,
    const float* __restrict__ tab, unsigned short* __restrict__ qbuf,
    unsigned short* __restrict__ kbuf, unsigned short* __restrict__ vtb) {
  __shared__ __align__(16) unsigned short As[128 * 32];
  __shared__ __align__(16) unsigned short Bs[128 * 32];
  int t = threadIdx.x;
  int lane = t & 63, w = t >> 6;
  int wr = w >> 1, wc = w & 1;
  int g = lane >> 4, r = lane & 15;
  int gx = gridDim.x;
  int nwg = gx * gridDim.y;
  int lin = blockIdx.y * gx + blockIdx.x;
  int cpx = nwg >> 3;
  int swz = (lin & 7) * cpx + (lin >> 3);
  int bx = swz % gx, by = swz / gx;
  long long rowBase = LL(by) * 128;
  long long colBase = LL(bx) * 128;

  f32x4 acc[4][4] = {};

  int c0 = t, c1 = t + 256;
  const unsigned short* ag0 = A + (rowBase + (c0 >> 2)) * K + (c0 & 3) * 8;
  const unsigned short* ag1 = A + (rowBase + (c1 >> 2)) * K + (c1 & 3) * 8;
  const unsigned short* bg0 = Bt + (colBase + (c0 >> 2)) * K + (c0 & 3) * 8;
  const unsigned short* bg1 = Bt + (colBase + (c1 >> 2)) * K + (c1 & 3) * 8;
  char* lA0 = (char*)As + c0 * 16; char* lA1 = (char*)As + c1 * 16;
  char* lB0 = (char*)Bs + c0 * 16; char* lB1 = (char*)Bs + c1 * 16;

  for (int kt = 0; kt < K; kt += 32) {
    __syncthreads();
    gload16(ag0 + kt, lA0);
    gload16(ag1 + kt, lA1);
    gload16(bg0 + kt, lB0);
    gload16(bg1 + kt, lB1);
    __syncthreads();

    bf16x8 af[4], bfr[4];
#pragma unroll
    for (int m = 0; m < 4; m++)
      af[m] = *(const bf16x8*)(const void*)(As + (wr * 64 + m * 16 + r) * 32 + g * 8);
#pragma unroll
    for (int n = 0; n < 4; n++)
      bfr[n] = *(const bf16x8*)(const void*)(Bs + (wc * 64 + n * 16 + r) * 32 + g * 8);
#pragma unroll
    for (int m = 0; m < 4; m++)
#pragma unroll
      for (int n = 0; n < 4; n++)
        acc[m][n] = __builtin_amdgcn_mfma_f32_16x16x32_bf16(af[m], bfr[n], acc[m][n], 0, 0, 0);
  }

  if (MODE == 0) {
#pragma unroll
    for (int m = 0; m < 4; m++)
#pragma unroll
      for (int n = 0; n < 4; n++) {
        long long row0 = rowBase + wr * 64 + m * 16 + g * 4;
        long long col = colBase + wc * 64 + n * 16 + r;
#pragma unroll
        for (int j = 0; j < 4; j++)
          ((float*)Cout)[(row0 + j) * N + col] = acc[m][n][j];
      }
  } else {
#pragma unroll
    for (int n = 0; n < 4; n++) {
      int gc0 = (int)colBase + wc * 64 + n * 16;  // uniform 16-col block
      int gc = gc0 + r;
      if (gc0 < 2560) {
        unsigned short* dst; int dcol, dstride; float scale;
        if (gc0 < 2048) { dst = qbuf; dcol = gc;        dstride = DIM; scale = 0.18033688f; }
        else            { dst = kbuf; dcol = gc - 2048; dstride = 512; scale = 1.0f; }
        int f = (gc & 63) >> 1;
        float sgn = (gc & 1) ? 1.f : -1.f;
#pragma unroll
        for (int m = 0; m < 4; m++) {
          long long row0 = rowBase + wr * 64 + m * 16 + g * 4;
#pragma unroll
          for (int j = 0; j < 4; j++) {
            float v = acc[m][n][j];
            float part = __shfl_xor(v, 1);
            int s = (int)((row0 + j) & (S_LEN - 1));
            float cc = tab[(s * 32 + f) * 2], ss = tab[(s * 32 + f) * 2 + 1];
            float o = (v * cc + sgn * part * ss) * scale;
            dst[(row0 + j) * dstride + dcol] = bfb(o);
          }
        }
      } else {
        // v: write transposed -> vt[(b*512 + dcol)][s], dcol = kvh*64+d
        int dcol = gc - 2560;
#pragma unroll
        for (int m = 0; m < 4; m++) {
          long long row0 = rowBase + wr * 64 + m * 16 + g * 4;
#pragma unroll
          for (int j = 0; j < 4; j++) {
            long long row = row0 + j;                  // b*2048 + s
            long long bq = row >> 11;
            int s = (int)(row & (S_LEN - 1));
            vtb[(bq * 512 + dcol) * S_LEN + s] = bfb(acc[m][n][j]);
          }
        }
      }
    }
  }
}

// ---- causal GQA flash attention, 32x32 MFMA, split-KV ----
// 1536 blocks (1D grid), LPT order. Jobs [0,1024): split halves of st>=8
// (t-range [0,st+1) or [st+1,2st+2)), longest (st=15) first; write
// normalized bf16 partial [64 d][128 row] + (m,l)/row. Jobs [1024,1536):
// unsplit st 0..7, longest first; write zb directly. kvh = lin&7 (XCD).
// Inner loop identical to R10/R11. launch_bounds(256,2): ~80 VGPR.
__global__ __launch_bounds__(256, 2) void k_attn(
    const unsigned short* __restrict__ qb, const unsigned short* __restrict__ kb,
    const unsigned short* __restrict__ vt, unsigned short* __restrict__ zb,
    unsigned short* __restrict__ obuf, float* __restrict__ mlbuf) {
  int lin = blockIdx.x;        // 0..1535
  int kvh = lin & 7;           // XCD-aligned K/V working set
  int st, b, hj, half, tt0, tt1;
  if (lin < 1024) {
    int s2 = lin >> 3;
    half = s2 & 1;
    int rem = s2 >> 1;
    hj = rem & 3;
    b = (rem >> 2) & 1;
    st = 15 - ((rem >> 3) & 7);     // 15..8, longest first
    tt0 = half ? (st + 1) : 0;
    tt1 = half ? (2 * st + 2) : (st + 1);
  } else {
    int u = (lin - 1024) >> 3;
    hj = u & 3;
    b = (u >> 2) & 1;
    st = 7 - ((u >> 3) & 7);        // 7..0, longest first
    half = 0;
    tt0 = 0; tt1 = 2 * st + 2;
  }
  int h = kvh * 4 + hj;
  int bh = b * NKV + kvh;

  int t = threadIdx.x, lane = t & 63, w = t >> 6;
  int l31 = lane & 31, hi = lane >> 5;
  int sw = (l31 & 7) * 8;      // ushort-index XOR swizzle (16B granule, 128B rows)

  __shared__ __align__(16) unsigned short Ks[2][64 * 64];  // [key][d]  swizzled
  __shared__ __align__(16) unsigned short Vs[2][64 * 64];  // [d][key]  swizzled

  // staging chunks: c -> row=c>>3, slot=c&7; source slot ^= row&7
  int c0 = t, c1 = t + 256;
  const unsigned short* kg0 = kb + LL(b) * S_LEN * 512 + (c0 >> 3) * 512 + kvh * HD
                                 + (((c0 & 7) ^ ((c0 >> 3) & 7)) * 8);
  const unsigned short* kg1 = kb + LL(b) * S_LEN * 512 + (c1 >> 3) * 512 + kvh * HD
                                 + (((c1 & 7) ^ ((c1 >> 3) & 7)) * 8);
  const unsigned short* vg0 = vt + (LL(bh) * HD + (c0 >> 3)) * S_LEN
                                 + (((c0 & 7) ^ ((c0 >> 3) & 7)) * 8);
  const unsigned short* vg1 = vt + (LL(bh) * HD + (c1 >> 3)) * S_LEN
                                 + (((c1 & 7) ^ ((c1 >> 3) & 7)) * 8);

#define STAGE(bufi, kst_)                                              \
  {                                                                    \
    gload16(kg0 + LL(kst_) * 512, (char*)Ks[bufi] + c0 * 16);          \
    gload16(kg1 + LL(kst_) * 512, (char*)Ks[bufi] + c1 * 16);          \
    gload16(vg0 + (kst_), (char*)Vs[bufi] + c0 * 16);                  \
    gload16(vg1 + (kst_), (char*)Vs[bufi] + c1 * 16);                  \
  }

  int rowb = st * 128 + w * 32;         // wave's first q-row
  int qg = rowb + l31;                  // this lane's q-row
  long long qrow = LL(b) * S_LEN + qg;

  // Q fragments (pre-scaled by 0.125*log2e in GEMM epilogue):
  bf16x8 qf[4];
#pragma unroll
  for (int s = 0; s < 4; s++)
    qf[s] = *(const bf16x8*)(const void*)(qb + qrow * DIM + h * HD + s * 16 + hi * 8);

  f32x16 acc0 = {}, acc1 = {};   // O^T[db*32 + crow][qrow], db=0,1
  float mrun = -1e30f, lrun = 0.f;

  STAGE(0, tt0 * 64);
  for (int tt = tt0; tt < tt1; tt++) {
    int kst = tt * 64;
    int cur = (tt - tt0) & 1;
    if (tt + 1 < tt1) {
      STAGE(cur ^ 1, kst + 64);
      asm volatile("s_waitcnt vmcnt(4)" ::: "memory");  // tile tt landed
    } else {
      asm volatile("s_waitcnt vmcnt(0)" ::: "memory");
    }
    __builtin_amdgcn_s_barrier();
    __builtin_amdgcn_sched_barrier(0);

    // wave-uniform: does this tile intersect this wave's rows?
    if (kst <= rowb + 31) {
      const unsigned short* Kc = Ks[cur];
      const unsigned short* Vc = Vs[cur];

      bf16x8 kf[2][4];
#pragma unroll
      for (int kbi = 0; kbi < 2; kbi++)
#pragma unroll
        for (int s = 0; s < 4; s++)
          kf[kbi][s] = *(const bf16x8*)(const void*)(
              Kc + (kbi * 32 + l31) * 64 + ((s * 16 + hi * 8) ^ sw));

      // swapped QK^T: C[key][qrow]; col=l31 (qrow), key=(reg&3)+8*(reg>>2)+4*hi
      __builtin_amdgcn_s_setprio(1);
      f32x16 sc0 = {}, sc1 = {};
#pragma unroll
      for (int s = 0; s < 4; s++) {
        sc0 = __builtin_amdgcn_mfma_f32_32x32x16_bf16(kf[0][s], qf[s], sc0, 0, 0, 0);
        sc1 = __builtin_amdgcn_mfma_f32_32x32x16_bf16(kf[1][s], qf[s], sc1, 0, 0, 0);
      }
      __builtin_amdgcn_s_setprio(0);

      bf16x8 vf[8];
#pragma unroll
      for (int db = 0; db < 2; db++)
#pragma unroll
        for (int f = 0; f < 4; f++)
          vf[db * 4 + f] = *(const bf16x8*)(const void*)(
              Vc + (db * 32 + l31) * 64 + ((f * 16 + hi * 8) ^ sw));

      if (kst + 63 > rowb) {   // diagonal region: causal mask
#pragma unroll
        for (int q = 0; q < 16; q++) {
          int kl = (q & 3) + 8 * (q >> 2) + 4 * hi;
          if (kst + kl > qg) sc0[q] = -1e30f;
          if (kst + 32 + kl > qg) sc1[q] = -1e30f;
        }
      }

      // online softmax (exp2 domain), defer-max THR=12 (R4 exact).
      float pm = -1e30f;
#pragma unroll
      for (int q = 0; q < 16; q++) {
        pm = fmaxf(pm, sc0[q]);
        pm = fmaxf(pm, sc1[q]);
      }
      pm = fmaxf(pm, __shfl_xor(pm, 32));   // full row max (both halves)
      if (__any(pm > mrun + 12.0f)) {
        float mnew = fmaxf(mrun, pm);
        float al = exp2f(mrun - mnew);
        mrun = mnew;
        lrun *= al;
        acc0 *= al;
        acc1 *= al;
      }
      f32x16 pv0, pv1;
      float ls = 0.f;
#pragma unroll
      for (int q = 0; q < 16; q++) {
        pv0[q] = exp2f(sc0[q] - mrun);
        pv1[q] = exp2f(sc1[q] - mrun);
        ls += pv0[q] + pv1[q];
      }
      lrun += ls + __shfl_xor(ls, 32);      // full row sum

      // P -> PV B-frags in registers (R4-proven).
      bf16x8 pfr[4];
#pragma unroll
      for (int f = 0; f < 4; f++) {
        int qb_ = (f & 1) * 8;
        float e0, e1, e2, e3, e4, e5, e6, e7;
        if (f < 2) {
          e0 = pv0[qb_ + 0]; e1 = pv0[qb_ + 1]; e2 = pv0[qb_ + 2]; e3 = pv0[qb_ + 3];
          e4 = pv0[qb_ + 4]; e5 = pv0[qb_ + 5]; e6 = pv0[qb_ + 6]; e7 = pv0[qb_ + 7];
        } else {
          e0 = pv1[qb_ + 0]; e1 = pv1[qb_ + 1]; e2 = pv1[qb_ + 2]; e3 = pv1[qb_ + 3];
          e4 = pv1[qb_ + 4]; e5 = pv1[qb_ + 5]; e6 = pv1[qb_ + 6]; e7 = pv1[qb_ + 7];
        }
        unsigned a0 = cvtpk(e0, e1), a1 = cvtpk(e2, e3);   // keys +0..3 (own set)
        unsigned b0 = cvtpk(e4, e5), b1 = cvtpk(e6, e7);   // keys +8..11 (own set)
        unsigned y0 = __shfl_xor(hi ? a0 : b0, 32);
        unsigned y1 = __shfl_xor(hi ? a1 : b1, 32);
        u32x4 uu;
        uu[0] = hi ? y0 : a0;   // keys f*16 + hi*8 + {0,1}
        uu[1] = hi ? y1 : a1;   //                  + {2,3}
        uu[2] = hi ? b0 : y0;   //                  + {4,5}
        uu[3] = hi ? b1 : y1;   //                  + {6,7}
        pfr[f] = *(bf16x8*)&uu;
      }

      // PV swapped: O^T += V^T x P^T
      __builtin_amdgcn_s_setprio(1);
#pragma unroll
      for (int f = 0; f < 4; f++) {
        acc0 = __builtin_amdgcn_mfma_f32_32x32x16_bf16(vf[f],     pfr[f], acc0, 0, 0, 0);
        acc1 = __builtin_amdgcn_mfma_f32_32x32x16_bf16(vf[4 + f], pfr[f], acc1, 0, 0, 0);
      }
      __builtin_amdgcn_s_setprio(0);
    }

    __builtin_amdgcn_sched_barrier(0);
    __builtin_amdgcn_s_barrier();   // all readers done before buffer reuse
  }

  float invl = 1.0f / lrun;
  if (lin >= 1024) {
    // unsplit: write z[qrow][h*64 + d], d = db*32 + 8*q4 + 4*hi + (0..3)
#pragma unroll
    for (int q4 = 0; q4 < 4; q4++) {
      uint2 u;
      u.x = cvtpk(acc0[q4 * 4 + 0] * invl, acc0[q4 * 4 + 1] * invl);
      u.y = cvtpk(acc0[q4 * 4 + 2] * invl, acc0[q4 * 4 + 3] * invl);
      *(uint2*)(void*)(zb + qrow * DIM + h * HD + 8 * q4 + 4 * hi) = u;
      uint2 v;
      v.x = cvtpk(acc1[q4 * 4 + 0] * invl, acc1[q4 * 4 + 1] * invl);
      v.y = cvtpk(acc1[q4 * 4 + 2] * invl, acc1[q4 * 4 + 3] * invl);
      *(uint2*)(void*)(zb + qrow * DIM + h * HD + 32 + 8 * q4 + 4 * hi) = v;
    }
  } else {
    // split half: normalized bf16 partial [64 d][128 row] + (m,l) per row
    int grp2 = ((b * 32 + h) * 8 + (st - 8)) * 2 + half;
    unsigned short* ob = obuf + LL(grp2) * 8192;
    int row = w * 32 + l31;
#pragma unroll
    for (int q4 = 0; q4 < 4; q4++) {
#pragma unroll
      for (int jj = 0; jj < 4; jj++) {
        int d0 = 8 * q4 + 4 * hi + jj;
        ob[d0 * 128 + row]        = bfb(acc0[q4 * 4 + jj] * invl);
        ob[(d0 + 32) * 128 + row] = bfb(acc1[q4 * 4 + jj] * invl);
      }
    }
    if (hi == 0) {
      mlbuf[grp2 * 256 + row] = mrun;
      mlbuf[grp2 * 256 + 128 + row] = lrun;
    }
  }
#undef STAGE
}

// ---- split-KV combine: merge 2 normalized partials per (b,h,st>=8) ----
__global__ __launch_bounds__(256) void k_comb(
    const unsigned short* __restrict__ obuf, const float* __restrict__ mlbuf,
    unsigned short* __restrict__ zb) {
  int g = blockIdx.x;          // 0..511 = (b*32+h)*8 + (st-8)
  int st = 8 + (g & 7);
  int bh = g >> 3;
  int h = bh & 31, b = bh >> 5;
  int t = threadIdx.x;
  int row = t >> 1;
  int dbase = (t & 1) * 32;
  const unsigned short* o0 = obuf + LL(g) * 2 * 8192;
  const unsigned short* o1 = o0 + 8192;
  float m0 = mlbuf[(g * 2 + 0) * 256 + row];
  float l0 = mlbuf[(g * 2 + 0) * 256 + 128 + row];
  float m1 = mlbuf[(g * 2 + 1) * 256 + row];
  float l1 = mlbuf[(g * 2 + 1) * 256 + 128 + row];
  float m = fmaxf(m0, m1);
  float w0 = l0 * exp2f(m0 - m);
  float w1 = l1 * exp2f(m1 - m);
  float inv = 1.0f / (w0 + w1);
  w0 *= inv; w1 *= inv;
  long long zoff = (LL(b) * S_LEN + st * 128 + row) * DIM + h * HD + dbase;
#pragma unroll
  for (int d = 0; d < 32; d += 2) {
    float f0 = bf2f(o0[(dbase + d) * 128 + row]) * w0
             + bf2f(o1[(dbase + d) * 128 + row]) * w1;
    float f1 = bf2f(o0[(dbase + d + 1) * 128 + row]) * w0
             + bf2f(o1[(dbase + d + 1) * 128 + row]) * w1;
    *(unsigned*)(void*)(zb + zoff + d) = cvtpk(f0, f1);
  }
}

extern "C" void kernel_launch(void* const* d_in, const int* in_sizes, int n_in,
                              void* d_out, int out_size, void* d_ws, size_t ws_size,
                              hipStream_t stream) {
  const float* x  = (const float*)d_in[0];
  const float* Wq = (const float*)d_in[2];
  const float* Wk = (const float*)d_in[3];
  const float* Wv = (const float*)d_in[4];
  const float* Wo = (const float*)d_in[5];
  float* out = (float*)d_out;

  char* wsb = (char*)d_ws;
  size_t off = 0;
  auto alloc = [&](size_t bytes) {
    void* p = wsb + off;
    off += (bytes + 255) & ~(size_t)255;
    return p;
  };
  float* tab            = (float*)alloc(LL(S_LEN) * 32 * 2 * 4);
  unsigned short* xb    = (unsigned short*)alloc(LL(BS) * DIM * 2);
  unsigned short* wqkvt = (unsigned short*)alloc(LL(NQKV) * DIM * 2);
  unsigned short* wot   = (unsigned short*)alloc(LL(DIM) * DIM * 2);
  unsigned short* qbuf  = (unsigned short*)alloc(LL(BS) * DIM * 2);
  unsigned short* kbuf  = (unsigned short*)alloc(LL(BS) * (NKV * HD) * 2);
  unsigned short* vtb   = (unsigned short*)alloc(LL(2 * NKV) * HD * S_LEN * 2);
  unsigned short* zb    = (unsigned short*)alloc(LL(BS) * DIM * 2);
  unsigned short* obuf  = (unsigned short*)alloc(LL(1024) * 8192 * 2);  // 16MB partials
  float* mlbuf          = (float*)alloc(LL(1024) * 256 * 4);            // 1MB (m,l)

  // fused preprocessing: rope table + x cast + 4 weight transposes
  k_prep<<<18688, 256, 0, stream>>>(x, Wq, Wk, Wv, Wo, tab, xb, wqkvt, wot);

  k_gemm<2><<<dim3(NQKV / 128, BS / 128), 256, 0, stream>>>(
      xb, wqkvt, nullptr, BS, NQKV, DIM, tab, qbuf, kbuf, vtb);

  k_attn<<<1536, 256, 0, stream>>>(qbuf, kbuf, vtb, zb, obuf, mlbuf);

  k_comb<<<512, 256, 0, stream>>>(obuf, mlbuf, zb);

  k_gemm<0><<<dim3(DIM / 128, BS / 128), 256, 0, stream>>>(
      zb, wot, out, BS, DIM, DIM, nullptr, nullptr, nullptr, nullptr);
}

// Round 14
// 197.587 us; speedup vs baseline: 1.0714x; 1.0714x over previous
//
#include <hip/hip_runtime.h>
#include <hip/hip_bf16.h>

// GQA prefill: x@[Wq|Wk|Wv] (rope fused) -> causal GQA flash attention -> @Wo
// B=2 S=2048 D=2048 H=32 Hkv=8 hd=64 G=4. All GEMMs bf16-MFMA, fp32 accum.
// R14: R11 base (best: 198.0us; LPT grid, 4 blocks/CU) + P-pack via
// v_permlane32_swap_b32 with CORRECTED operand order. R6's failure isolated
// the HW semantic as vdst.high <-> vsrc.low; under it swap(a0,b0) yields
// a0=[own{0,1}|partner{8,9}]=uu[0], b0=[partner{4,5}|own{12,13}]=uu[2].
// Replaces 8 shfl_xor + ~24 cndmask per tile with 8 permlane (VALU pipe).

#define S_LEN 2048
#define DIM   2048
#define NH    32
#define NKV   8
#define HD    64
#define BS    4096      // B*S rows
#define NQKV  3072      // 2048 q + 512 k + 512 v
#define LL(x) ((long long)(x))

typedef __bf16 bf16x8 __attribute__((ext_vector_type(8)));
typedef float  f32x4  __attribute__((ext_vector_type(4)));
typedef float  f32x16 __attribute__((ext_vector_type(16)));
typedef unsigned u32x4 __attribute__((ext_vector_type(4)));

__device__ __forceinline__ unsigned short bfb(float f) {
  __hip_bfloat16 h = __float2bfloat16(f);
  return *reinterpret_cast<unsigned short*>(&h);
}

__device__ __forceinline__ unsigned cvtpk(float lo, float hi) {
  unsigned u;
  asm("v_cvt_pk_bf16_f32 %0, %1, %2" : "=v"(u) : "v"(lo), "v"(hi));
  return u;
}

__device__ __forceinline__ void gload16(const void* g, void* l) {
  __builtin_amdgcn_global_load_lds(
      (const __attribute__((address_space(1))) void*)g,
      (__attribute__((address_space(3))) void*)l, 16, 0, 0);
}

// ---- fused preprocessing: rope table + x cast + 4 weight transposes ----
// block ranges: [0,256) rope | [256,8448) cast4 | [8448,12544) Wq tcast |
// [12544,13568) Wk | [13568,14592) Wv | [14592,18688) Wo.
__device__ __forceinline__ void tcast_body(
    const float* __restrict__ in, unsigned short* __restrict__ out,
    int K, int N, int bx, int by, int tid, float* tile /*[32][33]*/) {
  int n0 = bx * 32, k0 = by * 32;
  int tx = tid & 31, ty = tid >> 5;  // 32x8
#pragma unroll
  for (int r = 0; r < 32; r += 8)
    tile[(ty + r) * 33 + tx] = in[LL(k0 + ty + r) * N + n0 + tx];
  __syncthreads();
#pragma unroll
  for (int r = 0; r < 32; r += 8)
    out[LL(n0 + ty + r) * K + k0 + tx] = bfb(tile[tx * 33 + ty + r]);
}

__global__ __launch_bounds__(256) void k_prep(
    const float* __restrict__ x,  const float* __restrict__ Wq,
    const float* __restrict__ Wk, const float* __restrict__ Wv,
    const float* __restrict__ Wo, float* __restrict__ tab,
    unsigned short* __restrict__ xb, unsigned short* __restrict__ wqkvt,
    unsigned short* __restrict__ wot) {
  __shared__ float tile[32 * 33];
  int blk = blockIdx.x, tid = threadIdx.x;
  if (blk < 256) {
    // rope cos/sin table: [2048][32][2] f32 (double trig for accuracy)
    int i = blk * 256 + tid;             // 65536 exact
    int s = i >> 5, f = i & 31;
    double inv = pow(500000.0, -2.0 * (double)f / 64.0);
    double fr = (double)s * inv;
    tab[2 * i]     = (float)cos(fr);
    tab[2 * i + 1] = (float)sin(fr);
  } else if (blk < 8448) {
    // fp32 -> bf16 cast, 4-wide: n4 = BS*DIM/4 = 2097152 = 8192*256 exact
    int i = (blk - 256) * 256 + tid;
    float4 v = ((const float4*)x)[i];
    ushort4 o;
    o.x = bfb(v.x); o.y = bfb(v.y); o.z = bfb(v.z); o.w = bfb(v.w);
    ((ushort4*)xb)[i] = o;
  } else if (blk < 12544) {
    int t2 = blk - 8448;                 // Wq: grid (64,64)
    tcast_body(Wq, wqkvt, DIM, DIM, t2 & 63, t2 >> 6, tid, tile);
  } else if (blk < 13568) {
    int t3 = blk - 12544;                // Wk: grid (16,64)
    tcast_body(Wk, wqkvt + LL(2048) * DIM, DIM, 512, t3 & 15, t3 >> 4, tid, tile);
  } else if (blk < 14592) {
    int t4 = blk - 13568;                // Wv: grid (16,64)
    tcast_body(Wv, wqkvt + LL(2560) * DIM, DIM, 512, t4 & 15, t4 >> 4, tid, tile);
  } else {
    int t5 = blk - 14592;                // Wo: grid (64,64)
    tcast_body(Wo, wot, DIM, DIM, t5 & 63, t5 >> 6, tid, tile);
  }
}

// ---- bf16 MFMA GEMM: C[M][N] = A[M][K] * Bt[N][K]^T  (m97 structure + T1 swizzle) ----
// MODE 0: fp32 out. MODE 2: fused QKV epilogue (rope on q/k cols, split
// outputs; v cols written TRANSPOSED into vt[(b*512+dcol)][s]).
template <int MODE>
__global__ __launch_bounds__(256, 2) void k_gemm(
    const unsigned short* __restrict__ A, const unsigned short* __restrict__ Bt,
    void* __restrict__ Cout, int M, int N, int K,
    const float* __restrict__ tab, unsigned short* __restrict__ qbuf,
    unsigned short* __restrict__ kbuf, unsigned short* __restrict__ vtb) {
  __shared__ __align__(16) unsigned short As[128 * 32];
  __shared__ __align__(16) unsigned short Bs[128 * 32];
  int t = threadIdx.x;
  int lane = t & 63, w = t >> 6;
  int wr = w >> 1, wc = w & 1;
  int g = lane >> 4, r = lane & 15;
  // XCD-aware bijective swizzle (nwg % 8 == 0 for all our launches)
  int gx = gridDim.x;
  int nwg = gx * gridDim.y;
  int lin = blockIdx.y * gx + blockIdx.x;
  int cpx = nwg >> 3;
  int swz = (lin & 7) * cpx + (lin >> 3);
  int bx = swz % gx, by = swz / gx;
  long long rowBase = LL(by) * 128;
  long long colBase = LL(bx) * 128;

  f32x4 acc[4][4] = {};

  int c0 = t, c1 = t + 256;
  const unsigned short* ag0 = A + (rowBase + (c0 >> 2)) * K + (c0 & 3) * 8;
  const unsigned short* ag1 = A + (rowBase + (c1 >> 2)) * K + (c1 & 3) * 8;
  const unsigned short* bg0 = Bt + (colBase + (c0 >> 2)) * K + (c0 & 3) * 8;
  const unsigned short* bg1 = Bt + (colBase + (c1 >> 2)) * K + (c1 & 3) * 8;
  char* lA0 = (char*)As + c0 * 16; char* lA1 = (char*)As + c1 * 16;
  char* lB0 = (char*)Bs + c0 * 16; char* lB1 = (char*)Bs + c1 * 16;

  for (int kt = 0; kt < K; kt += 32) {
    __syncthreads();
    gload16(ag0 + kt, lA0);
    gload16(ag1 + kt, lA1);
    gload16(bg0 + kt, lB0);
    gload16(bg1 + kt, lB1);
    __syncthreads();

    bf16x8 af[4], bfr[4];
#pragma unroll
    for (int m = 0; m < 4; m++)
      af[m] = *(const bf16x8*)(const void*)(As + (wr * 64 + m * 16 + r) * 32 + g * 8);
#pragma unroll
    for (int n = 0; n < 4; n++)
      bfr[n] = *(const bf16x8*)(const void*)(Bs + (wc * 64 + n * 16 + r) * 32 + g * 8);
#pragma unroll
    for (int m = 0; m < 4; m++)
#pragma unroll
      for (int n = 0; n < 4; n++)
        acc[m][n] = __builtin_amdgcn_mfma_f32_16x16x32_bf16(af[m], bfr[n], acc[m][n], 0, 0, 0);
  }

  if (MODE == 0) {
#pragma unroll
    for (int m = 0; m < 4; m++)
#pragma unroll
      for (int n = 0; n < 4; n++) {
        long long row0 = rowBase + wr * 64 + m * 16 + g * 4;
        long long col = colBase + wc * 64 + n * 16 + r;
#pragma unroll
        for (int j = 0; j < 4; j++)
          ((float*)Cout)[(row0 + j) * N + col] = acc[m][n][j];
      }
  } else {
    // fused QKV epilogue. cols: [0,2048) q (rope, *0.125*log2e),
    // [2048,2560) k (rope), [2560,3072) v (plain, TRANSPOSED write).
    // rope: partner value in lane r^1.
#pragma unroll
    for (int n = 0; n < 4; n++) {
      int gc0 = (int)colBase + wc * 64 + n * 16;  // uniform 16-col block
      int gc = gc0 + r;
      if (gc0 < 2560) {
        unsigned short* dst; int dcol, dstride; float scale;
        if (gc0 < 2048) { dst = qbuf; dcol = gc;        dstride = DIM; scale = 0.18033688f; }
        else            { dst = kbuf; dcol = gc - 2048; dstride = 512; scale = 1.0f; }
        int f = (gc & 63) >> 1;
        float sgn = (gc & 1) ? 1.f : -1.f;
#pragma unroll
        for (int m = 0; m < 4; m++) {
          long long row0 = rowBase + wr * 64 + m * 16 + g * 4;
#pragma unroll
          for (int j = 0; j < 4; j++) {
            float v = acc[m][n][j];
            float part = __shfl_xor(v, 1);
            int s = (int)((row0 + j) & (S_LEN - 1));
            float cc = tab[(s * 32 + f) * 2], ss = tab[(s * 32 + f) * 2 + 1];
            float o = (v * cc + sgn * part * ss) * scale;
            dst[(row0 + j) * dstride + dcol] = bfb(o);
          }
        }
      } else {
        // v: write transposed -> vt[(b*512 + dcol)][s], dcol = kvh*64+d
        int dcol = gc - 2560;
#pragma unroll
        for (int m = 0; m < 4; m++) {
          long long row0 = rowBase + wr * 64 + m * 16 + g * 4;
#pragma unroll
          for (int j = 0; j < 4; j++) {
            long long row = row0 + j;                  // b*2048 + s
            long long bq = row >> 11;
            int s = (int)(row & (S_LEN - 1));
            vtb[(bq * 512 + dcol) * S_LEN + s] = bfb(acc[m][n][j]);
          }
        }
      }
    }
  }
}

// ---- causal GQA flash attention, 32x32 MFMA, in-register softmax + P ----
// R11 grid (best measured): (16, NH, 2) = 1024 blocks, LPT order
// (st = 15 - (idx>>3): longest blocks dispatch first), kvh = lin&7 (XCD).
// Block 256 (4 waves x 32 q-rows = 128-row supertile), nt = 2*st+2 tiles.
// launch_bounds(256,2): ~80 VGPR, no spills; 4 blocks/CU fit in HW.
// P-pack: v_permlane32_swap_b32 (vdst.high <-> vsrc.low), corrected order.
__global__ __launch_bounds__(256, 2) void k_attn(
    const unsigned short* __restrict__ qb, const unsigned short* __restrict__ kb,
    const unsigned short* __restrict__ vt, unsigned short* __restrict__ zb) {
  int lin = blockIdx.x + 16 * (blockIdx.y + 32 * blockIdx.z);  // 0..1023
  int kvh = lin & 7;           // XCD-aligned K/V working set
  int idx = lin >> 3;          // 0..127
  int st = 15 - (idx >> 3);    // LPT: low lin (early dispatch) = long block
  int b = (idx >> 2) & 1;
  int h = kvh * 4 + (idx & 3);
  int bh = b * NKV + kvh;

  int t = threadIdx.x, lane = t & 63, w = t >> 6;
  int l31 = lane & 31, hi = lane >> 5;
  int sw = (l31 & 7) * 8;      // ushort-index XOR swizzle (16B granule, 128B rows)

  __shared__ __align__(16) unsigned short Ks[2][64 * 64];  // [key][d]  swizzled
  __shared__ __align__(16) unsigned short Vs[2][64 * 64];  // [d][key]  swizzled

  // staging chunks: c -> row=c>>3, slot=c&7; source slot ^= row&7
  int c0 = t, c1 = t + 256;
  const unsigned short* kg0 = kb + LL(b) * S_LEN * 512 + (c0 >> 3) * 512 + kvh * HD
                                 + (((c0 & 7) ^ ((c0 >> 3) & 7)) * 8);
  const unsigned short* kg1 = kb + LL(b) * S_LEN * 512 + (c1 >> 3) * 512 + kvh * HD
                                 + (((c1 & 7) ^ ((c1 >> 3) & 7)) * 8);
  const unsigned short* vg0 = vt + (LL(bh) * HD + (c0 >> 3)) * S_LEN
                                 + (((c0 & 7) ^ ((c0 >> 3) & 7)) * 8);
  const unsigned short* vg1 = vt + (LL(bh) * HD + (c1 >> 3)) * S_LEN
                                 + (((c1 & 7) ^ ((c1 >> 3) & 7)) * 8);

#define STAGE(bufi, kst_)                                              \
  {                                                                    \
    gload16(kg0 + LL(kst_) * 512, (char*)Ks[bufi] + c0 * 16);          \
    gload16(kg1 + LL(kst_) * 512, (char*)Ks[bufi] + c1 * 16);          \
    gload16(vg0 + (kst_), (char*)Vs[bufi] + c0 * 16);                  \
    gload16(vg1 + (kst_), (char*)Vs[bufi] + c1 * 16);                  \
  }

  int rowb = st * 128 + w * 32;         // wave's first q-row
  int qg = rowb + l31;                  // this lane's q-row
  long long qrow = LL(b) * S_LEN + qg;

  // Q fragments (pre-scaled by 0.125*log2e in GEMM epilogue):
  // qf[s] elem e = Q[qrow][s*16 + hi*8 + e]  (B-frag: col=l31, k=hi*8+e)
  bf16x8 qf[4];
#pragma unroll
  for (int s = 0; s < 4; s++)
    qf[s] = *(const bf16x8*)(const void*)(qb + qrow * DIM + h * HD + s * 16 + hi * 8);

  f32x16 acc0 = {}, acc1 = {};   // O^T[db*32 + crow][qrow], db=0,1
  float mrun = -1e30f, lrun = 0.f;

  int nt = 2 * st + 2;
  STAGE(0, 0);
  for (int tt = 0; tt < nt; tt++) {
    int kst = tt * 64;
    int cur = tt & 1;
    if (tt + 1 < nt) {
      STAGE(cur ^ 1, kst + 64);
      asm volatile("s_waitcnt vmcnt(4)" ::: "memory");  // tile tt landed
    } else {
      asm volatile("s_waitcnt vmcnt(0)" ::: "memory");
    }
    __builtin_amdgcn_s_barrier();
    __builtin_amdgcn_sched_barrier(0);

    // wave-uniform: does this tile intersect this wave's rows?
    if (kst <= rowb + 31) {
      const unsigned short* Kc = Ks[cur];
      const unsigned short* Vc = Vs[cur];

      // K A-frags: kf[kbi][s] elem e = K[kbi*32+l31][s*16 + hi*8 + e]
      bf16x8 kf[2][4];
#pragma unroll
      for (int kbi = 0; kbi < 2; kbi++)
#pragma unroll
        for (int s = 0; s < 4; s++)
          kf[kbi][s] = *(const bf16x8*)(const void*)(
              Kc + (kbi * 32 + l31) * 64 + ((s * 16 + hi * 8) ^ sw));

      // swapped QK^T: C[key][qrow]; col=l31 (qrow), key=(reg&3)+8*(reg>>2)+4*hi
      __builtin_amdgcn_s_setprio(1);
      f32x16 sc0 = {}, sc1 = {};
#pragma unroll
      for (int s = 0; s < 4; s++) {
        sc0 = __builtin_amdgcn_mfma_f32_32x32x16_bf16(kf[0][s], qf[s], sc0, 0, 0, 0);
        sc1 = __builtin_amdgcn_mfma_f32_32x32x16_bf16(kf[1][s], qf[s], sc1, 0, 0, 0);
      }
      __builtin_amdgcn_s_setprio(0);

      // V A-frags hoisted (no dep on P): vf[db*4+f] elem e =
      // V^T[db*32+l31][f*16 + hi*8 + e]
      bf16x8 vf[8];
#pragma unroll
      for (int db = 0; db < 2; db++)
#pragma unroll
        for (int f = 0; f < 4; f++)
          vf[db * 4 + f] = *(const bf16x8*)(const void*)(
              Vc + (db * 32 + l31) * 64 + ((f * 16 + hi * 8) ^ sw));

      if (kst + 63 > rowb) {   // diagonal region: causal mask
#pragma unroll
        for (int q = 0; q < 16; q++) {
          int kl = (q & 3) + 8 * (q >> 2) + 4 * hi;
          if (kst + kl > qg) sc0[q] = -1e30f;
          if (kst + 32 + kl > qg) sc1[q] = -1e30f;
        }
      }

      // online softmax (exp2 domain), defer-max THR=12 (R4 exact).
      float pm = -1e30f;
#pragma unroll
      for (int q = 0; q < 16; q++) {
        pm = fmaxf(pm, sc0[q]);
        pm = fmaxf(pm, sc1[q]);
      }
      pm = fmaxf(pm, __shfl_xor(pm, 32));   // full row max (both halves)
      if (__any(pm > mrun + 12.0f)) {
        float mnew = fmaxf(mrun, pm);
        float al = exp2f(mrun - mnew);
        mrun = mnew;
        lrun *= al;
        acc0 *= al;
        acc1 *= al;
      }
      f32x16 pv0, pv1;
      float ls = 0.f;
#pragma unroll
      for (int q = 0; q < 16; q++) {
        pv0[q] = exp2f(sc0[q] - mrun);
        pv1[q] = exp2f(sc1[q] - mrun);
        ls += pv0[q] + pv1[q];
      }
      lrun += ls + __shfl_xor(ls, 32);      // full row sum

      // P -> PV B-frags via v_permlane32_swap_b32 (corrected operand order).
      // Own regs: a0 = keys 4hi+{0,1}, a1 = 4hi+{2,3}, b0 = 8+4hi+{0,1},
      // b1 = 8+4hi+{2,3} per 16-key group. HW semantic (from R6 failure
      // signature): swap(vdst,vsrc) exchanges vdst.high <-> vsrc.low.
      // swap(a0,b0): a0 = [lo:{0,1} | hi:{8,9}] = uu[0];
      //              b0 = [lo:{4,5} | hi:{12,13}] = uu[2]. Same for a1/b1.
      bf16x8 pfr[4];
#pragma unroll
      for (int f = 0; f < 4; f++) {
        int qb_ = (f & 1) * 8;
        float e0, e1, e2, e3, e4, e5, e6, e7;
        if (f < 2) {
          e0 = pv0[qb_ + 0]; e1 = pv0[qb_ + 1]; e2 = pv0[qb_ + 2]; e3 = pv0[qb_ + 3];
          e4 = pv0[qb_ + 4]; e5 = pv0[qb_ + 5]; e6 = pv0[qb_ + 6]; e7 = pv0[qb_ + 7];
        } else {
          e0 = pv1[qb_ + 0]; e1 = pv1[qb_ + 1]; e2 = pv1[qb_ + 2]; e3 = pv1[qb_ + 3];
          e4 = pv1[qb_ + 4]; e5 = pv1[qb_ + 5]; e6 = pv1[qb_ + 6]; e7 = pv1[qb_ + 7];
        }
        unsigned a0 = cvtpk(e0, e1), a1 = cvtpk(e2, e3);   // keys 4hi+{0..3}
        unsigned b0 = cvtpk(e4, e5), b1 = cvtpk(e6, e7);   // keys 8+4hi+{0..3}
        asm volatile("v_permlane32_swap_b32 %0, %1" : "+v"(a0), "+v"(b0));
        asm volatile("v_permlane32_swap_b32 %0, %1" : "+v"(a1), "+v"(b1));
        u32x4 uu;
        uu[0] = a0;   // keys f*16 + hi*8 + {0,1}
        uu[1] = a1;   //                  + {2,3}
        uu[2] = b0;   //                  + {4,5}
        uu[3] = b1;   //                  + {6,7}
        pfr[f] = *(bf16x8*)&uu;
      }

      // PV swapped: O^T += V^T x P^T
      __builtin_amdgcn_s_setprio(1);
#pragma unroll
      for (int f = 0; f < 4; f++) {
        acc0 = __builtin_amdgcn_mfma_f32_32x32x16_bf16(vf[f],     pfr[f], acc0, 0, 0, 0);
        acc1 = __builtin_amdgcn_mfma_f32_32x32x16_bf16(vf[4 + f], pfr[f], acc1, 0, 0, 0);
      }
      __builtin_amdgcn_s_setprio(0);
    }

    __builtin_amdgcn_sched_barrier(0);
    __builtin_amdgcn_s_barrier();   // all readers done before buffer reuse
  }

  // write z[qrow][h*64 + d], d = db*32 + 8*q4 + 4*hi + (0..3)
  float invl = 1.0f / lrun;
#pragma unroll
  for (int q4 = 0; q4 < 4; q4++) {
    uint2 u;
    u.x = cvtpk(acc0[q4 * 4 + 0] * invl, acc0[q4 * 4 + 1] * invl);
    u.y = cvtpk(acc0[q4 * 4 + 2] * invl, acc0[q4 * 4 + 3] * invl);
    *(uint2*)(void*)(zb + qrow * DIM + h * HD + 8 * q4 + 4 * hi) = u;
    uint2 v;
    v.x = cvtpk(acc1[q4 * 4 + 0] * invl, acc1[q4 * 4 + 1] * invl);
    v.y = cvtpk(acc1[q4 * 4 + 2] * invl, acc1[q4 * 4 + 3] * invl);
    *(uint2*)(void*)(zb + qrow * DIM + h * HD + 32 + 8 * q4 + 4 * hi) = v;
  }
#undef STAGE
}

extern "C" void kernel_launch(void* const* d_in, const int* in_sizes, int n_in,
                              void* d_out, int out_size, void* d_ws, size_t ws_size,
                              hipStream_t stream) {
  const float* x  = (const float*)d_in[0];
  const float* Wq = (const float*)d_in[2];
  const float* Wk = (const float*)d_in[3];
  const float* Wv = (const float*)d_in[4];
  const float* Wo = (const float*)d_in[5];
  float* out = (float*)d_out;

  char* wsb = (char*)d_ws;
  size_t off = 0;
  auto alloc = [&](size_t bytes) {
    void* p = wsb + off;
    off += (bytes + 255) & ~(size_t)255;
    return p;
  };
  float* tab            = (float*)alloc(LL(S_LEN) * 32 * 2 * 4);
  unsigned short* xb    = (unsigned short*)alloc(LL(BS) * DIM * 2);
  unsigned short* wqkvt = (unsigned short*)alloc(LL(NQKV) * DIM * 2);
  unsigned short* wot   = (unsigned short*)alloc(LL(DIM) * DIM * 2);
  unsigned short* qbuf  = (unsigned short*)alloc(LL(BS) * DIM * 2);
  unsigned short* kbuf  = (unsigned short*)alloc(LL(BS) * (NKV * HD) * 2);
  unsigned short* vtb   = (unsigned short*)alloc(LL(2 * NKV) * HD * S_LEN * 2);
  unsigned short* zb    = (unsigned short*)alloc(LL(BS) * DIM * 2);

  // fused preprocessing: rope table + x cast + 4 weight transposes
  k_prep<<<18688, 256, 0, stream>>>(x, Wq, Wk, Wv, Wo, tab, xb, wqkvt, wot);

  k_gemm<2><<<dim3(NQKV / 128, BS / 128), 256, 0, stream>>>(
      xb, wqkvt, nullptr, BS, NQKV, DIM, tab, qbuf, kbuf, vtb);

  k_attn<<<dim3(16, NH, 2), 256, 0, stream>>>(qbuf, kbuf, vtb, zb);

  k_gemm<0><<<dim3(DIM / 128, BS / 128), 256, 0, stream>>>(
      zb, wot, out, BS, DIM, DIM, nullptr, nullptr, nullptr, nullptr);
}

// Round 15
// 195.226 us; speedup vs baseline: 1.0843x; 1.0121x over previous
//
#include <hip/hip_runtime.h>
#include <hip/hip_bf16.h>

// GQA prefill: x@[Wq|Wk|Wv] (rope fused) -> causal GQA flash attention -> @Wo
// B=2 S=2048 D=2048 H=32 Hkv=8 hd=64 G=4. All GEMMs bf16-MFMA, fp32 accum.
// R15: single-barrier double-buffer rotation in k_attn. STAGE moved AFTER
// the top barrier: any wave past the barrier has drained its reads of
// buf[cur^1] (lgkm waits precede consuming MFMAs), so STAGE(tt+1->cur^1)
// cannot race. Saves 1 s_barrier + 1 sched_barrier per KV tile (33/block).
// Overlap depth preserved (loads issued before compute, waited next iter).
// Everything else byte-identical to R14 (197.6us best).

#define S_LEN 2048
#define DIM   2048
#define NH    32
#define NKV   8
#define HD    64
#define BS    4096      // B*S rows
#define NQKV  3072      // 2048 q + 512 k + 512 v
#define LL(x) ((long long)(x))

typedef __bf16 bf16x8 __attribute__((ext_vector_type(8)));
typedef float  f32x4  __attribute__((ext_vector_type(4)));
typedef float  f32x16 __attribute__((ext_vector_type(16)));
typedef unsigned u32x4 __attribute__((ext_vector_type(4)));

__device__ __forceinline__ unsigned short bfb(float f) {
  __hip_bfloat16 h = __float2bfloat16(f);
  return *reinterpret_cast<unsigned short*>(&h);
}

__device__ __forceinline__ unsigned cvtpk(float lo, float hi) {
  unsigned u;
  asm("v_cvt_pk_bf16_f32 %0, %1, %2" : "=v"(u) : "v"(lo), "v"(hi));
  return u;
}

__device__ __forceinline__ void gload16(const void* g, void* l) {
  __builtin_amdgcn_global_load_lds(
      (const __attribute__((address_space(1))) void*)g,
      (__attribute__((address_space(3))) void*)l, 16, 0, 0);
}

// ---- fused preprocessing: rope table + x cast + 4 weight transposes ----
// block ranges: [0,256) rope | [256,8448) cast4 | [8448,12544) Wq tcast |
// [12544,13568) Wk | [13568,14592) Wv | [14592,18688) Wo.
__device__ __forceinline__ void tcast_body(
    const float* __restrict__ in, unsigned short* __restrict__ out,
    int K, int N, int bx, int by, int tid, float* tile /*[32][33]*/) {
  int n0 = bx * 32, k0 = by * 32;
  int tx = tid & 31, ty = tid >> 5;  // 32x8
#pragma unroll
  for (int r = 0; r < 32; r += 8)
    tile[(ty + r) * 33 + tx] = in[LL(k0 + ty + r) * N + n0 + tx];
  __syncthreads();
#pragma unroll
  for (int r = 0; r < 32; r += 8)
    out[LL(n0 + ty + r) * K + k0 + tx] = bfb(tile[tx * 33 + ty + r]);
}

__global__ __launch_bounds__(256) void k_prep(
    const float* __restrict__ x,  const float* __restrict__ Wq,
    const float* __restrict__ Wk, const float* __restrict__ Wv,
    const float* __restrict__ Wo, float* __restrict__ tab,
    unsigned short* __restrict__ xb, unsigned short* __restrict__ wqkvt,
    unsigned short* __restrict__ wot) {
  __shared__ float tile[32 * 33];
  int blk = blockIdx.x, tid = threadIdx.x;
  if (blk < 256) {
    // rope cos/sin table: [2048][32][2] f32 (double trig for accuracy)
    int i = blk * 256 + tid;             // 65536 exact
    int s = i >> 5, f = i & 31;
    double inv = pow(500000.0, -2.0 * (double)f / 64.0);
    double fr = (double)s * inv;
    tab[2 * i]     = (float)cos(fr);
    tab[2 * i + 1] = (float)sin(fr);
  } else if (blk < 8448) {
    // fp32 -> bf16 cast, 4-wide: n4 = BS*DIM/4 = 2097152 = 8192*256 exact
    int i = (blk - 256) * 256 + tid;
    float4 v = ((const float4*)x)[i];
    ushort4 o;
    o.x = bfb(v.x); o.y = bfb(v.y); o.z = bfb(v.z); o.w = bfb(v.w);
    ((ushort4*)xb)[i] = o;
  } else if (blk < 12544) {
    int t2 = blk - 8448;                 // Wq: grid (64,64)
    tcast_body(Wq, wqkvt, DIM, DIM, t2 & 63, t2 >> 6, tid, tile);
  } else if (blk < 13568) {
    int t3 = blk - 12544;                // Wk: grid (16,64)
    tcast_body(Wk, wqkvt + LL(2048) * DIM, DIM, 512, t3 & 15, t3 >> 4, tid, tile);
  } else if (blk < 14592) {
    int t4 = blk - 13568;                // Wv: grid (16,64)
    tcast_body(Wv, wqkvt + LL(2560) * DIM, DIM, 512, t4 & 15, t4 >> 4, tid, tile);
  } else {
    int t5 = blk - 14592;                // Wo: grid (64,64)
    tcast_body(Wo, wot, DIM, DIM, t5 & 63, t5 >> 6, tid, tile);
  }
}

// ---- bf16 MFMA GEMM: C[M][N] = A[M][K] * Bt[N][K]^T  (m97 structure + T1 swizzle) ----
// MODE 0: fp32 out. MODE 2: fused QKV epilogue (rope on q/k cols, split
// outputs; v cols written TRANSPOSED into vt[(b*512+dcol)][s]).
template <int MODE>
__global__ __launch_bounds__(256, 2) void k_gemm(
    const unsigned short* __restrict__ A, const unsigned short* __restrict__ Bt,
    void* __restrict__ Cout, int M, int N, int K,
    const float* __restrict__ tab, unsigned short* __restrict__ qbuf,
    unsigned short* __restrict__ kbuf, unsigned short* __restrict__ vtb) {
  __shared__ __align__(16) unsigned short As[128 * 32];
  __shared__ __align__(16) unsigned short Bs[128 * 32];
  int t = threadIdx.x;
  int lane = t & 63, w = t >> 6;
  int wr = w >> 1, wc = w & 1;
  int g = lane >> 4, r = lane & 15;
  // XCD-aware bijective swizzle (nwg % 8 == 0 for all our launches)
  int gx = gridDim.x;
  int nwg = gx * gridDim.y;
  int lin = blockIdx.y * gx + blockIdx.x;
  int cpx = nwg >> 3;
  int swz = (lin & 7) * cpx + (lin >> 3);
  int bx = swz % gx, by = swz / gx;
  long long rowBase = LL(by) * 128;
  long long colBase = LL(bx) * 128;

  f32x4 acc[4][4] = {};

  int c0 = t, c1 = t + 256;
  const unsigned short* ag0 = A + (rowBase + (c0 >> 2)) * K + (c0 & 3) * 8;
  const unsigned short* ag1 = A + (rowBase + (c1 >> 2)) * K + (c1 & 3) * 8;
  const unsigned short* bg0 = Bt + (colBase + (c0 >> 2)) * K + (c0 & 3) * 8;
  const unsigned short* bg1 = Bt + (colBase + (c1 >> 2)) * K + (c1 & 3) * 8;
  char* lA0 = (char*)As + c0 * 16; char* lA1 = (char*)As + c1 * 16;
  char* lB0 = (char*)Bs + c0 * 16; char* lB1 = (char*)Bs + c1 * 16;

  for (int kt = 0; kt < K; kt += 32) {
    __syncthreads();
    gload16(ag0 + kt, lA0);
    gload16(ag1 + kt, lA1);
    gload16(bg0 + kt, lB0);
    gload16(bg1 + kt, lB1);
    __syncthreads();

    bf16x8 af[4], bfr[4];
#pragma unroll
    for (int m = 0; m < 4; m++)
      af[m] = *(const bf16x8*)(const void*)(As + (wr * 64 + m * 16 + r) * 32 + g * 8);
#pragma unroll
    for (int n = 0; n < 4; n++)
      bfr[n] = *(const bf16x8*)(const void*)(Bs + (wc * 64 + n * 16 + r) * 32 + g * 8);
#pragma unroll
    for (int m = 0; m < 4; m++)
#pragma unroll
      for (int n = 0; n < 4; n++)
        acc[m][n] = __builtin_amdgcn_mfma_f32_16x16x32_bf16(af[m], bfr[n], acc[m][n], 0, 0, 0);
  }

  if (MODE == 0) {
#pragma unroll
    for (int m = 0; m < 4; m++)
#pragma unroll
      for (int n = 0; n < 4; n++) {
        long long row0 = rowBase + wr * 64 + m * 16 + g * 4;
        long long col = colBase + wc * 64 + n * 16 + r;
#pragma unroll
        for (int j = 0; j < 4; j++)
          ((float*)Cout)[(row0 + j) * N + col] = acc[m][n][j];
      }
  } else {
    // fused QKV epilogue. cols: [0,2048) q (rope, *0.125*log2e),
    // [2048,2560) k (rope), [2560,3072) v (plain, TRANSPOSED write).
    // rope: partner value in lane r^1.
#pragma unroll
    for (int n = 0; n < 4; n++) {
      int gc0 = (int)colBase + wc * 64 + n * 16;  // uniform 16-col block
      int gc = gc0 + r;
      if (gc0 < 2560) {
        unsigned short* dst; int dcol, dstride; float scale;
        if (gc0 < 2048) { dst = qbuf; dcol = gc;        dstride = DIM; scale = 0.18033688f; }
        else            { dst = kbuf; dcol = gc - 2048; dstride = 512; scale = 1.0f; }
        int f = (gc & 63) >> 1;
        float sgn = (gc & 1) ? 1.f : -1.f;
#pragma unroll
        for (int m = 0; m < 4; m++) {
          long long row0 = rowBase + wr * 64 + m * 16 + g * 4;
#pragma unroll
          for (int j = 0; j < 4; j++) {
            float v = acc[m][n][j];
            float part = __shfl_xor(v, 1);
            int s = (int)((row0 + j) & (S_LEN - 1));
            float cc = tab[(s * 32 + f) * 2], ss = tab[(s * 32 + f) * 2 + 1];
            float o = (v * cc + sgn * part * ss) * scale;
            dst[(row0 + j) * dstride + dcol] = bfb(o);
          }
        }
      } else {
        // v: write transposed -> vt[(b*512 + dcol)][s], dcol = kvh*64+d
        int dcol = gc - 2560;
#pragma unroll
        for (int m = 0; m < 4; m++) {
          long long row0 = rowBase + wr * 64 + m * 16 + g * 4;
#pragma unroll
          for (int j = 0; j < 4; j++) {
            long long row = row0 + j;                  // b*2048 + s
            long long bq = row >> 11;
            int s = (int)(row & (S_LEN - 1));
            vtb[(bq * 512 + dcol) * S_LEN + s] = bfb(acc[m][n][j]);
          }
        }
      }
    }
  }
}

// ---- causal GQA flash attention, 32x32 MFMA, in-register softmax + P ----
// R11 grid: (16, NH, 2) = 1024 blocks, LPT order (st = 15 - (idx>>3)),
// kvh = lin&7 (XCD). Block 256 (4 waves x 32 q-rows = 128-row supertile),
// nt = 2*st+2 tiles. launch_bounds(256,2): ~80 VGPR, 4 blocks/CU in HW.
// R15: ONE barrier per tile (STAGE after barrier; rotation-safe, see top).
__global__ __launch_bounds__(256, 2) void k_attn(
    const unsigned short* __restrict__ qb, const unsigned short* __restrict__ kb,
    const unsigned short* __restrict__ vt, unsigned short* __restrict__ zb) {
  int lin = blockIdx.x + 16 * (blockIdx.y + 32 * blockIdx.z);  // 0..1023
  int kvh = lin & 7;           // XCD-aligned K/V working set
  int idx = lin >> 3;          // 0..127
  int st = 15 - (idx >> 3);    // LPT: low lin (early dispatch) = long block
  int b = (idx >> 2) & 1;
  int h = kvh * 4 + (idx & 3);
  int bh = b * NKV + kvh;

  int t = threadIdx.x, lane = t & 63, w = t >> 6;
  int l31 = lane & 31, hi = lane >> 5;
  int sw = (l31 & 7) * 8;      // ushort-index XOR swizzle (16B granule, 128B rows)

  __shared__ __align__(16) unsigned short Ks[2][64 * 64];  // [key][d]  swizzled
  __shared__ __align__(16) unsigned short Vs[2][64 * 64];  // [d][key]  swizzled

  // staging chunks: c -> row=c>>3, slot=c&7; source slot ^= row&7
  int c0 = t, c1 = t + 256;
  const unsigned short* kg0 = kb + LL(b) * S_LEN * 512 + (c0 >> 3) * 512 + kvh * HD
                                 + (((c0 & 7) ^ ((c0 >> 3) & 7)) * 8);
  const unsigned short* kg1 = kb + LL(b) * S_LEN * 512 + (c1 >> 3) * 512 + kvh * HD
                                 + (((c1 & 7) ^ ((c1 >> 3) & 7)) * 8);
  const unsigned short* vg0 = vt + (LL(bh) * HD + (c0 >> 3)) * S_LEN
                                 + (((c0 & 7) ^ ((c0 >> 3) & 7)) * 8);
  const unsigned short* vg1 = vt + (LL(bh) * HD + (c1 >> 3)) * S_LEN
                                 + (((c1 & 7) ^ ((c1 >> 3) & 7)) * 8);

#define STAGE(bufi, kst_)                                              \
  {                                                                    \
    gload16(kg0 + LL(kst_) * 512, (char*)Ks[bufi] + c0 * 16);          \
    gload16(kg1 + LL(kst_) * 512, (char*)Ks[bufi] + c1 * 16);          \
    gload16(vg0 + (kst_), (char*)Vs[bufi] + c0 * 16);                  \
    gload16(vg1 + (kst_), (char*)Vs[bufi] + c1 * 16);                  \
  }

  int rowb = st * 128 + w * 32;         // wave's first q-row
  int qg = rowb + l31;                  // this lane's q-row
  long long qrow = LL(b) * S_LEN + qg;

  // Q fragments (pre-scaled by 0.125*log2e in GEMM epilogue):
  // qf[s] elem e = Q[qrow][s*16 + hi*8 + e]  (B-frag: col=l31, k=hi*8+e)
  bf16x8 qf[4];
#pragma unroll
  for (int s = 0; s < 4; s++)
    qf[s] = *(const bf16x8*)(const void*)(qb + qrow * DIM + h * HD + s * 16 + hi * 8);

  f32x16 acc0 = {}, acc1 = {};   // O^T[db*32 + crow][qrow], db=0,1
  float mrun = -1e30f, lrun = 0.f;

  int nt = 2 * st + 2;
  STAGE(0, 0);
  for (int tt = 0; tt < nt; tt++) {
    int kst = tt * 64;
    int cur = tt & 1;
    // own tile-tt loads landed; barrier makes it all-waves AND guarantees
    // every wave has drained its reads of buf[cur^1] (tile tt-1).
    asm volatile("s_waitcnt vmcnt(0)" ::: "memory");
    __builtin_amdgcn_s_barrier();
    __builtin_amdgcn_sched_barrier(0);
    // safe to overwrite buf[cur^1] now; loads fly under tile tt's compute.
    if (tt + 1 < nt) STAGE(cur ^ 1, kst + 64);

    // wave-uniform: does this tile intersect this wave's rows?
    if (kst <= rowb + 31) {
      const unsigned short* Kc = Ks[cur];
      const unsigned short* Vc = Vs[cur];

      // K A-frags: kf[kbi][s] elem e = K[kbi*32+l31][s*16 + hi*8 + e]
      bf16x8 kf[2][4];
#pragma unroll
      for (int kbi = 0; kbi < 2; kbi++)
#pragma unroll
        for (int s = 0; s < 4; s++)
          kf[kbi][s] = *(const bf16x8*)(const void*)(
              Kc + (kbi * 32 + l31) * 64 + ((s * 16 + hi * 8) ^ sw));

      // swapped QK^T: C[key][qrow]; col=l31 (qrow), key=(reg&3)+8*(reg>>2)+4*hi
      __builtin_amdgcn_s_setprio(1);
      f32x16 sc0 = {}, sc1 = {};
#pragma unroll
      for (int s = 0; s < 4; s++) {
        sc0 = __builtin_amdgcn_mfma_f32_32x32x16_bf16(kf[0][s], qf[s], sc0, 0, 0, 0);
        sc1 = __builtin_amdgcn_mfma_f32_32x32x16_bf16(kf[1][s], qf[s], sc1, 0, 0, 0);
      }
      __builtin_amdgcn_s_setprio(0);

      // V A-frags hoisted (no dep on P): vf[db*4+f] elem e =
      // V^T[db*32+l31][f*16 + hi*8 + e]
      bf16x8 vf[8];
#pragma unroll
      for (int db = 0; db < 2; db++)
#pragma unroll
        for (int f = 0; f < 4; f++)
          vf[db * 4 + f] = *(const bf16x8*)(const void*)(
              Vc + (db * 32 + l31) * 64 + ((f * 16 + hi * 8) ^ sw));

      if (kst + 63 > rowb) {   // diagonal region: causal mask
#pragma unroll
        for (int q = 0; q < 16; q++) {
          int kl = (q & 3) + 8 * (q >> 2) + 4 * hi;
          if (kst + kl > qg) sc0[q] = -1e30f;
          if (kst + 32 + kl > qg) sc1[q] = -1e30f;
        }
      }

      // online softmax (exp2 domain), defer-max THR=12 (R4 exact).
      float pm = -1e30f;
#pragma unroll
      for (int q = 0; q < 16; q++) {
        pm = fmaxf(pm, sc0[q]);
        pm = fmaxf(pm, sc1[q]);
      }
      pm = fmaxf(pm, __shfl_xor(pm, 32));   // full row max (both halves)
      if (__any(pm > mrun + 12.0f)) {
        float mnew = fmaxf(mrun, pm);
        float al = exp2f(mrun - mnew);
        mrun = mnew;
        lrun *= al;
        acc0 *= al;
        acc1 *= al;
      }
      f32x16 pv0, pv1;
      float ls = 0.f;
#pragma unroll
      for (int q = 0; q < 16; q++) {
        pv0[q] = exp2f(sc0[q] - mrun);
        pv1[q] = exp2f(sc1[q] - mrun);
        ls += pv0[q] + pv1[q];
      }
      lrun += ls + __shfl_xor(ls, 32);      // full row sum

      // P -> PV B-frags via v_permlane32_swap_b32 (R14-verified semantic:
      // swap(vdst,vsrc) exchanges vdst.high <-> vsrc.low).
      // swap(a0,b0): a0 = [lo:{0,1} | hi:{8,9}] = uu[0];
      //              b0 = [lo:{4,5} | hi:{12,13}] = uu[2]. Same for a1/b1.
      bf16x8 pfr[4];
#pragma unroll
      for (int f = 0; f < 4; f++) {
        int qb_ = (f & 1) * 8;
        float e0, e1, e2, e3, e4, e5, e6, e7;
        if (f < 2) {
          e0 = pv0[qb_ + 0]; e1 = pv0[qb_ + 1]; e2 = pv0[qb_ + 2]; e3 = pv0[qb_ + 3];
          e4 = pv0[qb_ + 4]; e5 = pv0[qb_ + 5]; e6 = pv0[qb_ + 6]; e7 = pv0[qb_ + 7];
        } else {
          e0 = pv1[qb_ + 0]; e1 = pv1[qb_ + 1]; e2 = pv1[qb_ + 2]; e3 = pv1[qb_ + 3];
          e4 = pv1[qb_ + 4]; e5 = pv1[qb_ + 5]; e6 = pv1[qb_ + 6]; e7 = pv1[qb_ + 7];
        }
        unsigned a0 = cvtpk(e0, e1), a1 = cvtpk(e2, e3);   // keys 4hi+{0..3}
        unsigned b0 = cvtpk(e4, e5), b1 = cvtpk(e6, e7);   // keys 8+4hi+{0..3}
        asm volatile("v_permlane32_swap_b32 %0, %1" : "+v"(a0), "+v"(b0));
        asm volatile("v_permlane32_swap_b32 %0, %1" : "+v"(a1), "+v"(b1));
        u32x4 uu;
        uu[0] = a0;   // keys f*16 + hi*8 + {0,1}
        uu[1] = a1;   //                  + {2,3}
        uu[2] = b0;   //                  + {4,5}
        uu[3] = b1;   //                  + {6,7}
        pfr[f] = *(bf16x8*)&uu;
      }

      // PV swapped: O^T += V^T x P^T
      __builtin_amdgcn_s_setprio(1);
#pragma unroll
      for (int f = 0; f < 4; f++) {
        acc0 = __builtin_amdgcn_mfma_f32_32x32x16_bf16(vf[f],     pfr[f], acc0, 0, 0, 0);
        acc1 = __builtin_amdgcn_mfma_f32_32x32x16_bf16(vf[4 + f], pfr[f], acc1, 0, 0, 0);
      }
      __builtin_amdgcn_s_setprio(0);
    }
  }

  // write z[qrow][h*64 + d], d = db*32 + 8*q4 + 4*hi + (0..3)
  float invl = 1.0f / lrun;
#pragma unroll
  for (int q4 = 0; q4 < 4; q4++) {
    uint2 u;
    u.x = cvtpk(acc0[q4 * 4 + 0] * invl, acc0[q4 * 4 + 1] * invl);
    u.y = cvtpk(acc0[q4 * 4 + 2] * invl, acc0[q4 * 4 + 3] * invl);
    *(uint2*)(void*)(zb + qrow * DIM + h * HD + 8 * q4 + 4 * hi) = u;
    uint2 v;
    v.x = cvtpk(acc1[q4 * 4 + 0] * invl, acc1[q4 * 4 + 1] * invl);
    v.y = cvtpk(acc1[q4 * 4 + 2] * invl, acc1[q4 * 4 + 3] * invl);
    *(uint2*)(void*)(zb + qrow * DIM + h * HD + 32 + 8 * q4 + 4 * hi) = v;
  }
#undef STAGE
}

extern "C" void kernel_launch(void* const* d_in, const int* in_sizes, int n_in,
                              void* d_out, int out_size, void* d_ws, size_t ws_size,
                              hipStream_t stream) {
  const float* x  = (const float*)d_in[0];
  const float* Wq = (const float*)d_in[2];
  const float* Wk = (const float*)d_in[3];
  const float* Wv = (const float*)d_in[4];
  const float* Wo = (const float*)d_in[5];
  float* out = (float*)d_out;

  char* wsb = (char*)d_ws;
  size_t off = 0;
  auto alloc = [&](size_t bytes) {
    void* p = wsb + off;
    off += (bytes + 255) & ~(size_t)255;
    return p;
  };
  float* tab            = (float*)alloc(LL(S_LEN) * 32 * 2 * 4);
  unsigned short* xb    = (unsigned short*)alloc(LL(BS) * DIM * 2);
  unsigned short* wqkvt = (unsigned short*)alloc(LL(NQKV) * DIM * 2);
  unsigned short* wot   = (unsigned short*)alloc(LL(DIM) * DIM * 2);
  unsigned short* qbuf  = (unsigned short*)alloc(LL(BS) * DIM * 2);
  unsigned short* kbuf  = (unsigned short*)alloc(LL(BS) * (NKV * HD) * 2);
  unsigned short* vtb   = (unsigned short*)alloc(LL(2 * NKV) * HD * S_LEN * 2);
  unsigned short* zb    = (unsigned short*)alloc(LL(BS) * DIM * 2);

  // fused preprocessing: rope table + x cast + 4 weight transposes
  k_prep<<<18688, 256, 0, stream>>>(x, Wq, Wk, Wv, Wo, tab, xb, wqkvt, wot);

  k_gemm<2><<<dim3(NQKV / 128, BS / 128), 256, 0, stream>>>(
      xb, wqkvt, nullptr, BS, NQKV, DIM, tab, qbuf, kbuf, vtb);

  k_attn<<<dim3(16, NH, 2), 256, 0, stream>>>(qbuf, kbuf, vtb, zb);

  k_gemm<0><<<dim3(DIM / 128, BS / 128), 256, 0, stream>>>(
      zb, wot, out, BS, DIM, DIM, nullptr, nullptr, nullptr, nullptr);
}

// Round 16
// 187.700 us; speedup vs baseline: 1.1278x; 1.0401x over previous
//
#include <hip/hip_runtime.h>
#include <hip/hip_bf16.h>

// GQA prefill: x@[Wq|Wk|Wv] (rope fused) -> causal GQA flash attention -> @Wo
// B=2 S=2048 D=2048 H=32 Hkv=8 hd=64 G=4. All GEMMs bf16-MFMA, fp32 accum.
// R16: GEMM K-loop upgraded to BK=64 + XOR-swizzled LDS (attn-proven scheme,
// same 128B row width). Halves barrier/vmcnt-drain count (32 iters vs 64)
// and kills the 8-way ds_read_b128 bank conflict (SQ_LDS_BANK_CONFLICT was
// 6.29M/dispatch). 32KB LDS/block, still 2 blocks/CU. Epilogues unchanged.
// k_attn = R15 (single-barrier rotation, 195.2us best).

#define S_LEN 2048
#define DIM   2048
#define NH    32
#define NKV   8
#define HD    64
#define BS    4096      // B*S rows
#define NQKV  3072      // 2048 q + 512 k + 512 v
#define LL(x) ((long long)(x))

typedef __bf16 bf16x8 __attribute__((ext_vector_type(8)));
typedef float  f32x4  __attribute__((ext_vector_type(4)));
typedef float  f32x16 __attribute__((ext_vector_type(16)));
typedef unsigned u32x4 __attribute__((ext_vector_type(4)));

__device__ __forceinline__ unsigned short bfb(float f) {
  __hip_bfloat16 h = __float2bfloat16(f);
  return *reinterpret_cast<unsigned short*>(&h);
}

__device__ __forceinline__ unsigned cvtpk(float lo, float hi) {
  unsigned u;
  asm("v_cvt_pk_bf16_f32 %0, %1, %2" : "=v"(u) : "v"(lo), "v"(hi));
  return u;
}

__device__ __forceinline__ void gload16(const void* g, void* l) {
  __builtin_amdgcn_global_load_lds(
      (const __attribute__((address_space(1))) void*)g,
      (__attribute__((address_space(3))) void*)l, 16, 0, 0);
}

// ---- fused preprocessing: rope table + x cast + 4 weight transposes ----
// block ranges: [0,256) rope | [256,8448) cast4 | [8448,12544) Wq tcast |
// [12544,13568) Wk | [13568,14592) Wv | [14592,18688) Wo.
__device__ __forceinline__ void tcast_body(
    const float* __restrict__ in, unsigned short* __restrict__ out,
    int K, int N, int bx, int by, int tid, float* tile /*[32][33]*/) {
  int n0 = bx * 32, k0 = by * 32;
  int tx = tid & 31, ty = tid >> 5;  // 32x8
#pragma unroll
  for (int r = 0; r < 32; r += 8)
    tile[(ty + r) * 33 + tx] = in[LL(k0 + ty + r) * N + n0 + tx];
  __syncthreads();
#pragma unroll
  for (int r = 0; r < 32; r += 8)
    out[LL(n0 + ty + r) * K + k0 + tx] = bfb(tile[tx * 33 + ty + r]);
}

__global__ __launch_bounds__(256) void k_prep(
    const float* __restrict__ x,  const float* __restrict__ Wq,
    const float* __restrict__ Wk, const float* __restrict__ Wv,
    const float* __restrict__ Wo, float* __restrict__ tab,
    unsigned short* __restrict__ xb, unsigned short* __restrict__ wqkvt,
    unsigned short* __restrict__ wot) {
  __shared__ float tile[32 * 33];
  int blk = blockIdx.x, tid = threadIdx.x;
  if (blk < 256) {
    // rope cos/sin table: [2048][32][2] f32 (double trig for accuracy)
    int i = blk * 256 + tid;             // 65536 exact
    int s = i >> 5, f = i & 31;
    double inv = pow(500000.0, -2.0 * (double)f / 64.0);
    double fr = (double)s * inv;
    tab[2 * i]     = (float)cos(fr);
    tab[2 * i + 1] = (float)sin(fr);
  } else if (blk < 8448) {
    // fp32 -> bf16 cast, 4-wide: n4 = BS*DIM/4 = 2097152 = 8192*256 exact
    int i = (blk - 256) * 256 + tid;
    float4 v = ((const float4*)x)[i];
    ushort4 o;
    o.x = bfb(v.x); o.y = bfb(v.y); o.z = bfb(v.z); o.w = bfb(v.w);
    ((ushort4*)xb)[i] = o;
  } else if (blk < 12544) {
    int t2 = blk - 8448;                 // Wq: grid (64,64)
    tcast_body(Wq, wqkvt, DIM, DIM, t2 & 63, t2 >> 6, tid, tile);
  } else if (blk < 13568) {
    int t3 = blk - 12544;                // Wk: grid (16,64)
    tcast_body(Wk, wqkvt + LL(2048) * DIM, DIM, 512, t3 & 15, t3 >> 4, tid, tile);
  } else if (blk < 14592) {
    int t4 = blk - 13568;                // Wv: grid (16,64)
    tcast_body(Wv, wqkvt + LL(2560) * DIM, DIM, 512, t4 & 15, t4 >> 4, tid, tile);
  } else {
    int t5 = blk - 14592;                // Wo: grid (64,64)
    tcast_body(Wo, wot, DIM, DIM, t5 & 63, t5 >> 6, tid, tile);
  }
}

// ---- bf16 MFMA GEMM: C[M][N] = A[M][K] * Bt[N][K]^T ----
// R16: BK=64 K-loop, XOR-swizzled LDS ([128][64] shorts; slot ^= row&7 on
// stage, col ^ (r&7)*8 on read -> conflict-free ds_read_b128).
// MODE 0: fp32 out. MODE 2: fused QKV epilogue (rope on q/k cols, split
// outputs; v cols written TRANSPOSED into vt[(b*512+dcol)][s]).
template <int MODE>
__global__ __launch_bounds__(256, 2) void k_gemm(
    const unsigned short* __restrict__ A, const unsigned short* __restrict__ Bt,
    void* __restrict__ Cout, int M, int N, int K,
    const float* __restrict__ tab, unsigned short* __restrict__ qbuf,
    unsigned short* __restrict__ kbuf, unsigned short* __restrict__ vtb) {
  __shared__ __align__(16) unsigned short As[128 * 64];
  __shared__ __align__(16) unsigned short Bs[128 * 64];
  int t = threadIdx.x;
  int lane = t & 63, w = t >> 6;
  int wr = w >> 1, wc = w & 1;
  int g = lane >> 4, r = lane & 15;
  int sw = (r & 7) * 8;   // ushort-index XOR swizzle (16B granule, 128B rows)
  // XCD-aware bijective swizzle (nwg % 8 == 0 for all our launches)
  int gx = gridDim.x;
  int nwg = gx * gridDim.y;
  int lin = blockIdx.y * gx + blockIdx.x;
  int cpx = nwg >> 3;
  int swz = (lin & 7) * cpx + (lin >> 3);
  int bx = swz % gx, by = swz / gx;
  long long rowBase = LL(by) * 128;
  long long colBase = LL(bx) * 128;

  f32x4 acc[4][4] = {};

  // staging chunks: c in [0,1024): row=c>>3, slot=c&7; src col=(slot^(row&7))*8
  int c0 = t, c1 = t + 256, c2 = t + 512, c3 = t + 768;
#define SRCP(P, base, c) ((P) + ((base) + ((c) >> 3)) * K \
                               + ((((c) & 7) ^ (((c) >> 3) & 7)) * 8))
  const unsigned short* ag0 = SRCP(A, rowBase, c0);
  const unsigned short* ag1 = SRCP(A, rowBase, c1);
  const unsigned short* ag2 = SRCP(A, rowBase, c2);
  const unsigned short* ag3 = SRCP(A, rowBase, c3);
  const unsigned short* bg0 = SRCP(Bt, colBase, c0);
  const unsigned short* bg1 = SRCP(Bt, colBase, c1);
  const unsigned short* bg2 = SRCP(Bt, colBase, c2);
  const unsigned short* bg3 = SRCP(Bt, colBase, c3);
#undef SRCP
  char* lA0 = (char*)As + c0 * 16; char* lA1 = (char*)As + c1 * 16;
  char* lA2 = (char*)As + c2 * 16; char* lA3 = (char*)As + c3 * 16;
  char* lB0 = (char*)Bs + c0 * 16; char* lB1 = (char*)Bs + c1 * 16;
  char* lB2 = (char*)Bs + c2 * 16; char* lB3 = (char*)Bs + c3 * 16;

  for (int kt = 0; kt < K; kt += 64) {
    __syncthreads();
    gload16(ag0 + kt, lA0);
    gload16(ag1 + kt, lA1);
    gload16(ag2 + kt, lA2);
    gload16(ag3 + kt, lA3);
    gload16(bg0 + kt, lB0);
    gload16(bg1 + kt, lB1);
    gload16(bg2 + kt, lB2);
    gload16(bg3 + kt, lB3);
    __syncthreads();

#pragma unroll
    for (int kd = 0; kd < 2; kd++) {
      bf16x8 af[4], bfr[4];
#pragma unroll
      for (int m = 0; m < 4; m++)
        af[m] = *(const bf16x8*)(const void*)(
            As + (wr * 64 + m * 16 + r) * 64 + ((kd * 32 + g * 8) ^ sw));
#pragma unroll
      for (int n = 0; n < 4; n++)
        bfr[n] = *(const bf16x8*)(const void*)(
            Bs + (wc * 64 + n * 16 + r) * 64 + ((kd * 32 + g * 8) ^ sw));
#pragma unroll
      for (int m = 0; m < 4; m++)
#pragma unroll
        for (int n = 0; n < 4; n++)
          acc[m][n] = __builtin_amdgcn_mfma_f32_16x16x32_bf16(af[m], bfr[n], acc[m][n], 0, 0, 0);
    }
  }

  if (MODE == 0) {
#pragma unroll
    for (int m = 0; m < 4; m++)
#pragma unroll
      for (int n = 0; n < 4; n++) {
        long long row0 = rowBase + wr * 64 + m * 16 + g * 4;
        long long col = colBase + wc * 64 + n * 16 + r;
#pragma unroll
        for (int j = 0; j < 4; j++)
          ((float*)Cout)[(row0 + j) * N + col] = acc[m][n][j];
      }
  } else {
    // fused QKV epilogue. cols: [0,2048) q (rope, *0.125*log2e),
    // [2048,2560) k (rope), [2560,3072) v (plain, TRANSPOSED write).
    // rope: partner value in lane r^1.
#pragma unroll
    for (int n = 0; n < 4; n++) {
      int gc0 = (int)colBase + wc * 64 + n * 16;  // uniform 16-col block
      int gc = gc0 + r;
      if (gc0 < 2560) {
        unsigned short* dst; int dcol, dstride; float scale;
        if (gc0 < 2048) { dst = qbuf; dcol = gc;        dstride = DIM; scale = 0.18033688f; }
        else            { dst = kbuf; dcol = gc - 2048; dstride = 512; scale = 1.0f; }
        int f = (gc & 63) >> 1;
        float sgn = (gc & 1) ? 1.f : -1.f;
#pragma unroll
        for (int m = 0; m < 4; m++) {
          long long row0 = rowBase + wr * 64 + m * 16 + g * 4;
#pragma unroll
          for (int j = 0; j < 4; j++) {
            float v = acc[m][n][j];
            float part = __shfl_xor(v, 1);
            int s = (int)((row0 + j) & (S_LEN - 1));
            float cc = tab[(s * 32 + f) * 2], ss = tab[(s * 32 + f) * 2 + 1];
            float o = (v * cc + sgn * part * ss) * scale;
            dst[(row0 + j) * dstride + dcol] = bfb(o);
          }
        }
      } else {
        // v: write transposed -> vt[(b*512 + dcol)][s], dcol = kvh*64+d
        int dcol = gc - 2560;
#pragma unroll
        for (int m = 0; m < 4; m++) {
          long long row0 = rowBase + wr * 64 + m * 16 + g * 4;
#pragma unroll
          for (int j = 0; j < 4; j++) {
            long long row = row0 + j;                  // b*2048 + s
            long long bq = row >> 11;
            int s = (int)(row & (S_LEN - 1));
            vtb[(bq * 512 + dcol) * S_LEN + s] = bfb(acc[m][n][j]);
          }
        }
      }
    }
  }
}

// ---- causal GQA flash attention, 32x32 MFMA, in-register softmax + P ----
// R11 grid: (16, NH, 2) = 1024 blocks, LPT order (st = 15 - (idx>>3)),
// kvh = lin&7 (XCD). Block 256 (4 waves x 32 q-rows = 128-row supertile),
// nt = 2*st+2 tiles. launch_bounds(256,2): ~80 VGPR, 4 blocks/CU in HW.
// R15: ONE barrier per tile (STAGE after barrier; rotation-safe).
__global__ __launch_bounds__(256, 2) void k_attn(
    const unsigned short* __restrict__ qb, const unsigned short* __restrict__ kb,
    const unsigned short* __restrict__ vt, unsigned short* __restrict__ zb) {
  int lin = blockIdx.x + 16 * (blockIdx.y + 32 * blockIdx.z);  // 0..1023
  int kvh = lin & 7;           // XCD-aligned K/V working set
  int idx = lin >> 3;          // 0..127
  int st = 15 - (idx >> 3);    // LPT: low lin (early dispatch) = long block
  int b = (idx >> 2) & 1;
  int h = kvh * 4 + (idx & 3);
  int bh = b * NKV + kvh;

  int t = threadIdx.x, lane = t & 63, w = t >> 6;
  int l31 = lane & 31, hi = lane >> 5;
  int sw = (l31 & 7) * 8;      // ushort-index XOR swizzle (16B granule, 128B rows)

  __shared__ __align__(16) unsigned short Ks[2][64 * 64];  // [key][d]  swizzled
  __shared__ __align__(16) unsigned short Vs[2][64 * 64];  // [d][key]  swizzled

  // staging chunks: c -> row=c>>3, slot=c&7; source slot ^= row&7
  int c0 = t, c1 = t + 256;
  const unsigned short* kg0 = kb + LL(b) * S_LEN * 512 + (c0 >> 3) * 512 + kvh * HD
                                 + (((c0 & 7) ^ ((c0 >> 3) & 7)) * 8);
  const unsigned short* kg1 = kb + LL(b) * S_LEN * 512 + (c1 >> 3) * 512 + kvh * HD
                                 + (((c1 & 7) ^ ((c1 >> 3) & 7)) * 8);
  const unsigned short* vg0 = vt + (LL(bh) * HD + (c0 >> 3)) * S_LEN
                                 + (((c0 & 7) ^ ((c0 >> 3) & 7)) * 8);
  const unsigned short* vg1 = vt + (LL(bh) * HD + (c1 >> 3)) * S_LEN
                                 + (((c1 & 7) ^ ((c1 >> 3) & 7)) * 8);

#define STAGE(bufi, kst_)                                              \
  {                                                                    \
    gload16(kg0 + LL(kst_) * 512, (char*)Ks[bufi] + c0 * 16);          \
    gload16(kg1 + LL(kst_) * 512, (char*)Ks[bufi] + c1 * 16);          \
    gload16(vg0 + (kst_), (char*)Vs[bufi] + c0 * 16);                  \
    gload16(vg1 + (kst_), (char*)Vs[bufi] + c1 * 16);                  \
  }

  int rowb = st * 128 + w * 32;         // wave's first q-row
  int qg = rowb + l31;                  // this lane's q-row
  long long qrow = LL(b) * S_LEN + qg;

  // Q fragments (pre-scaled by 0.125*log2e in GEMM epilogue):
  // qf[s] elem e = Q[qrow][s*16 + hi*8 + e]  (B-frag: col=l31, k=hi*8+e)
  bf16x8 qf[4];
#pragma unroll
  for (int s = 0; s < 4; s++)
    qf[s] = *(const bf16x8*)(const void*)(qb + qrow * DIM + h * HD + s * 16 + hi * 8);

  f32x16 acc0 = {}, acc1 = {};   // O^T[db*32 + crow][qrow], db=0,1
  float mrun = -1e30f, lrun = 0.f;

  int nt = 2 * st + 2;
  STAGE(0, 0);
  for (int tt = 0; tt < nt; tt++) {
    int kst = tt * 64;
    int cur = tt & 1;
    // own tile-tt loads landed; barrier makes it all-waves AND guarantees
    // every wave has drained its reads of buf[cur^1] (tile tt-1).
    asm volatile("s_waitcnt vmcnt(0)" ::: "memory");
    __builtin_amdgcn_s_barrier();
    __builtin_amdgcn_sched_barrier(0);
    // safe to overwrite buf[cur^1] now; loads fly under tile tt's compute.
    if (tt + 1 < nt) STAGE(cur ^ 1, kst + 64);

    // wave-uniform: does this tile intersect this wave's rows?
    if (kst <= rowb + 31) {
      const unsigned short* Kc = Ks[cur];
      const unsigned short* Vc = Vs[cur];

      // K A-frags: kf[kbi][s] elem e = K[kbi*32+l31][s*16 + hi*8 + e]
      bf16x8 kf[2][4];
#pragma unroll
      for (int kbi = 0; kbi < 2; kbi++)
#pragma unroll
        for (int s = 0; s < 4; s++)
          kf[kbi][s] = *(const bf16x8*)(const void*)(
              Kc + (kbi * 32 + l31) * 64 + ((s * 16 + hi * 8) ^ sw));

      // swapped QK^T: C[key][qrow]; col=l31 (qrow), key=(reg&3)+8*(reg>>2)+4*hi
      __builtin_amdgcn_s_setprio(1);
      f32x16 sc0 = {}, sc1 = {};
#pragma unroll
      for (int s = 0; s < 4; s++) {
        sc0 = __builtin_amdgcn_mfma_f32_32x32x16_bf16(kf[0][s], qf[s], sc0, 0, 0, 0);
        sc1 = __builtin_amdgcn_mfma_f32_32x32x16_bf16(kf[1][s], qf[s], sc1, 0, 0, 0);
      }
      __builtin_amdgcn_s_setprio(0);

      // V A-frags hoisted (no dep on P): vf[db*4+f] elem e =
      // V^T[db*32+l31][f*16 + hi*8 + e]
      bf16x8 vf[8];
#pragma unroll
      for (int db = 0; db < 2; db++)
#pragma unroll
        for (int f = 0; f < 4; f++)
          vf[db * 4 + f] = *(const bf16x8*)(const void*)(
              Vc + (db * 32 + l31) * 64 + ((f * 16 + hi * 8) ^ sw));

      if (kst + 63 > rowb) {   // diagonal region: causal mask
#pragma unroll
        for (int q = 0; q < 16; q++) {
          int kl = (q & 3) + 8 * (q >> 2) + 4 * hi;
          if (kst + kl > qg) sc0[q] = -1e30f;
          if (kst + 32 + kl > qg) sc1[q] = -1e30f;
        }
      }

      // online softmax (exp2 domain), defer-max THR=12 (R4 exact).
      float pm = -1e30f;
#pragma unroll
      for (int q = 0; q < 16; q++) {
        pm = fmaxf(pm, sc0[q]);
        pm = fmaxf(pm, sc1[q]);
      }
      pm = fmaxf(pm, __shfl_xor(pm, 32));   // full row max (both halves)
      if (__any(pm > mrun + 12.0f)) {
        float mnew = fmaxf(mrun, pm);
        float al = exp2f(mrun - mnew);
        mrun = mnew;
        lrun *= al;
        acc0 *= al;
        acc1 *= al;
      }
      f32x16 pv0, pv1;
      float ls = 0.f;
#pragma unroll
      for (int q = 0; q < 16; q++) {
        pv0[q] = exp2f(sc0[q] - mrun);
        pv1[q] = exp2f(sc1[q] - mrun);
        ls += pv0[q] + pv1[q];
      }
      lrun += ls + __shfl_xor(ls, 32);      // full row sum

      // P -> PV B-frags via v_permlane32_swap_b32 (R14-verified semantic:
      // swap(vdst,vsrc) exchanges vdst.high <-> vsrc.low).
      // swap(a0,b0): a0 = [lo:{0,1} | hi:{8,9}] = uu[0];
      //              b0 = [lo:{4,5} | hi:{12,13}] = uu[2]. Same for a1/b1.
      bf16x8 pfr[4];
#pragma unroll
      for (int f = 0; f < 4; f++) {
        int qb_ = (f & 1) * 8;
        float e0, e1, e2, e3, e4, e5, e6, e7;
        if (f < 2) {
          e0 = pv0[qb_ + 0]; e1 = pv0[qb_ + 1]; e2 = pv0[qb_ + 2]; e3 = pv0[qb_ + 3];
          e4 = pv0[qb_ + 4]; e5 = pv0[qb_ + 5]; e6 = pv0[qb_ + 6]; e7 = pv0[qb_ + 7];
        } else {
          e0 = pv1[qb_ + 0]; e1 = pv1[qb_ + 1]; e2 = pv1[qb_ + 2]; e3 = pv1[qb_ + 3];
          e4 = pv1[qb_ + 4]; e5 = pv1[qb_ + 5]; e6 = pv1[qb_ + 6]; e7 = pv1[qb_ + 7];
        }
        unsigned a0 = cvtpk(e0, e1), a1 = cvtpk(e2, e3);   // keys 4hi+{0..3}
        unsigned b0 = cvtpk(e4, e5), b1 = cvtpk(e6, e7);   // keys 8+4hi+{0..3}
        asm volatile("v_permlane32_swap_b32 %0, %1" : "+v"(a0), "+v"(b0));
        asm volatile("v_permlane32_swap_b32 %0, %1" : "+v"(a1), "+v"(b1));
        u32x4 uu;
        uu[0] = a0;   // keys f*16 + hi*8 + {0,1}
        uu[1] = a1;   //                  + {2,3}
        uu[2] = b0;   //                  + {4,5}
        uu[3] = b1;   //                  + {6,7}
        pfr[f] = *(bf16x8*)&uu;
      }

      // PV swapped: O^T += V^T x P^T
      __builtin_amdgcn_s_setprio(1);
#pragma unroll
      for (int f = 0; f < 4; f++) {
        acc0 = __builtin_amdgcn_mfma_f32_32x32x16_bf16(vf[f],     pfr[f], acc0, 0, 0, 0);
        acc1 = __builtin_amdgcn_mfma_f32_32x32x16_bf16(vf[4 + f], pfr[f], acc1, 0, 0, 0);
      }
      __builtin_amdgcn_s_setprio(0);
    }
  }

  // write z[qrow][h*64 + d], d = db*32 + 8*q4 + 4*hi + (0..3)
  float invl = 1.0f / lrun;
#pragma unroll
  for (int q4 = 0; q4 < 4; q4++) {
    uint2 u;
    u.x = cvtpk(acc0[q4 * 4 + 0] * invl, acc0[q4 * 4 + 1] * invl);
    u.y = cvtpk(acc0[q4 * 4 + 2] * invl, acc0[q4 * 4 + 3] * invl);
    *(uint2*)(void*)(zb + qrow * DIM + h * HD + 8 * q4 + 4 * hi) = u;
    uint2 v;
    v.x = cvtpk(acc1[q4 * 4 + 0] * invl, acc1[q4 * 4 + 1] * invl);
    v.y = cvtpk(acc1[q4 * 4 + 2] * invl, acc1[q4 * 4 + 3] * invl);
    *(uint2*)(void*)(zb + qrow * DIM + h * HD + 32 + 8 * q4 + 4 * hi) = v;
  }
#undef STAGE
}

extern "C" void kernel_launch(void* const* d_in, const int* in_sizes, int n_in,
                              void* d_out, int out_size, void* d_ws, size_t ws_size,
                              hipStream_t stream) {
  const float* x  = (const float*)d_in[0];
  const float* Wq = (const float*)d_in[2];
  const float* Wk = (const float*)d_in[3];
  const float* Wv = (const float*)d_in[4];
  const float* Wo = (const float*)d_in[5];
  float* out = (float*)d_out;

  char* wsb = (char*)d_ws;
  size_t off = 0;
  auto alloc = [&](size_t bytes) {
    void* p = wsb + off;
    off += (bytes + 255) & ~(size_t)255;
    return p;
  };
  float* tab            = (float*)alloc(LL(S_LEN) * 32 * 2 * 4);
  unsigned short* xb    = (unsigned short*)alloc(LL(BS) * DIM * 2);
  unsigned short* wqkvt = (unsigned short*)alloc(LL(NQKV) * DIM * 2);
  unsigned short* wot   = (unsigned short*)alloc(LL(DIM) * DIM * 2);
  unsigned short* qbuf  = (unsigned short*)alloc(LL(BS) * DIM * 2);
  unsigned short* kbuf  = (unsigned short*)alloc(LL(BS) * (NKV * HD) * 2);
  unsigned short* vtb   = (unsigned short*)alloc(LL(2 * NKV) * HD * S_LEN * 2);
  unsigned short* zb    = (unsigned short*)alloc(LL(BS) * DIM * 2);

  // fused preprocessing: rope table + x cast + 4 weight transposes
  k_prep<<<18688, 256, 0, stream>>>(x, Wq, Wk, Wv, Wo, tab, xb, wqkvt, wot);

  k_gemm<2><<<dim3(NQKV / 128, BS / 128), 256, 0, stream>>>(
      xb, wqkvt, nullptr, BS, NQKV, DIM, tab, qbuf, kbuf, vtb);

  k_attn<<<dim3(16, NH, 2), 256, 0, stream>>>(qbuf, kbuf, vtb, zb);

  k_gemm<0><<<dim3(DIM / 128, BS / 128), 256, 0, stream>>>(
      zb, wot, out, BS, DIM, DIM, nullptr, nullptr, nullptr, nullptr);
}